// Round 8
// baseline (771.430 us; speedup 1.0000x reference)
//
#include <hip/hip_runtime.h>

#define B_ 8
#define N_ 1024
#define C_ 768
#define H_ 12
#define HD_ 64
#define NB_ 49
#define BH_ 96
#define SCALE_ 0.125f

typedef unsigned int u32;
typedef unsigned short u16;
typedef __attribute__((ext_vector_type(8))) short mfrag;   // 8 bf16 (4 VGPRs)
typedef __attribute__((ext_vector_type(4))) float f32x4;

__device__ __forceinline__ u16 f2bf(float x) {             // f32 -> bf16 (RNE)
    u32 u = __float_as_uint(x);
    u32 r = u + 0x7FFFu + ((u >> 16) & 1u);
    return (u16)(r >> 16);
}
__device__ __forceinline__ float bf2f(u16 h) { return __uint_as_float(((u32)h) << 16); }

// iRPE piecewise bucket (closed form for ALPHA=1.9, BETA=3.8, GAMMA=15.2):
// |d|: 0->0, 1->1, 2,3->2, >=4->3 ; bucket = 3 + sign(d)*g  (in [0,6])
__device__ __forceinline__ int lutf(int d) {
    int a = d < 0 ? -d : d;
    int gg = (a < 2 ? a : 2) + (a >= 4 ? 1 : 0);
    return d < 0 ? 3 - gg : 3 + gg;
}

// ---------------------------------------------------------------------------
// K1 (fused prep): per (bh, 4 rows):
//   - write q,k bf16 hi/lo buffers [bh][n][64]
//   - tk[bh][i][49] = q_i . w_rpe_k[:,u] ; tqT[bh][49][1024] = SCALE*k_j.w_rpe_q
// ---------------------------------------------------------------------------
__global__ void irpe_prep_k(const float* __restrict__ q, const float* __restrict__ k,
                            const float* __restrict__ w_rpe_q, const float* __restrict__ w_rpe_k,
                            u16* __restrict__ qh, u16* __restrict__ ql,
                            u16* __restrict__ kh, u16* __restrict__ kl,
                            float* __restrict__ tk, float* __restrict__ tqT) {
    const int bh = blockIdx.y, b = bh / H_, h = bh % H_;
    const int row0 = blockIdx.x * 4;
    __shared__ float qs[4][HD_], ks[4][HD_];
    const int t = threadIdx.x;
    {
        const int r = t >> 6, d = t & 63;
        const size_t gi = ((size_t)(b * N_ + row0 + r)) * C_ + h * HD_ + d;
        const float vq = q[gi], vk = k[gi];
        qs[r][d] = vq;
        ks[r][d] = vk;
        const size_t so = (((size_t)(bh << 10)) + row0 + r) * 64 + d;
        const u16 qhi = f2bf(vq), khi = f2bf(vk);
        qh[so] = qhi; ql[so] = f2bf(vq - bf2f(qhi));
        kh[so] = khi; kl[so] = f2bf(vk - bf2f(khi));
    }
    __syncthreads();
    if (t < 4 * NB_) {
        const int r = t / NB_, u = t - r * NB_;
        float dk = 0.f, dq = 0.f;
#pragma unroll
        for (int d = 0; d < HD_; ++d) {
            dk = fmaf(qs[r][d], w_rpe_k[d * NB_ + u], dk);
            dq = fmaf(ks[r][d], w_rpe_q[d * NB_ + u], dq);
        }
        tk[((size_t)bh * N_ + row0 + r) * NB_ + u] = dk;
        tqT[(((size_t)bh * NB_ + u) << 10) + row0 + r] = dq * SCALE_;
    }
}

// ---------------------------------------------------------------------------
// K0b: v -> transposed bf16 (hi only) [bh][64(d)][1024(j)]
// ---------------------------------------------------------------------------
__global__ void irpe_vt_k(const float* __restrict__ v, u16* __restrict__ vth) {
    __shared__ float tile[64][65];
    const int bh = blockIdx.y, jc0 = blockIdx.x * 64;
    const int b = bh / H_, h = bh % H_;
    const int t = threadIdx.x;
#pragma unroll
    for (int rep = 0; rep < 4; ++rep) {
        const int fl = rep * 256 + t;
        const int jr = fl >> 4, c4 = (fl & 15) * 4;
        const float4 x = *(const float4*)&v[((size_t)(b * N_ + jc0 + jr)) * C_ + h * HD_ + c4];
        tile[jr][c4] = x.x; tile[jr][c4 + 1] = x.y; tile[jr][c4 + 2] = x.z; tile[jr][c4 + 3] = x.w;
    }
    __syncthreads();
    const int d = t >> 2, jq = (t & 3) * 16;
    u32 ph[8];
#pragma unroll
    for (int jj = 0; jj < 8; ++jj) {
        const u16 h0 = f2bf(tile[jq + jj * 2][d]);
        const u16 h1 = f2bf(tile[jq + jj * 2 + 1][d]);
        ph[jj] = (u32)h0 | ((u32)h1 << 16);
    }
    const size_t dst = (((size_t)bh * 64 + d) << 10) + jc0 + jq;
    *(uint4*)&vth[dst] = make_uint4(ph[0], ph[1], ph[2], ph[3]);
    *(uint4*)&vth[dst + 8] = make_uint4(ph[4], ph[5], ph[6], ph[7]);
}

// ---------------------------------------------------------------------------
// K_main: single-sweep fused attention, bf16x3 QK / bf16 PV, wave-local P.
// Block = (bh, 64 i-rows), XCD-pinned. 4 waves; wave w owns rows w*16..+15 and
// all 4 j-tiles -> P write/read wave-local. 2 barriers/chunk. LDS ~51 KB ->
// 3 blocks/CU. attn written unnormalized (rescale kernel normalizes).
// ---------------------------------------------------------------------------
__global__ __launch_bounds__(256, 3) void irpe_attn_mfma_k(
    const u16* __restrict__ qh_g, const u16* __restrict__ ql_g,
    const u16* __restrict__ kh_g, const u16* __restrict__ kl_g,
    const u16* __restrict__ vth_g,
    const float* __restrict__ tk, const float* __restrict__ tqT,
    float* __restrict__ attn, float* __restrict__ s_arr, float* __restrict__ pre) {
    __shared__ u16 kAh[4096], kAl[4096];     // K  [64 j][64 d] swizzled  16 KB
    __shared__ u16 vAh[4096];                // vT [64 d][64 j] swizzled   8 KB
    __shared__ u16 awh[4096];                // P  [64 i][64 j] swizzled   8 KB
    __shared__ float tq_s[NB_ * 68];         // [49][68] f32            13.3 KB
    __shared__ u16 tks_s[64 * 50];           // [64][50] bf16            6.25 KB

    const int gid = blockIdx.x;
    const int xcd = gid & 7, L = gid >> 3;
    const int bh = xcd * 12 + (L >> 4);      // 12 bh per XCD, itile-inner
    const int itile = L & 15;
    const int b = bh / H_, h = bh % H_;
    const int i0 = itile * 64;
    const int t = threadIdx.x;
    const int w = t >> 6, lane = t & 63;
    const int ln4 = lane >> 4, lh15 = lane & 15;
    const int yi = itile * 2 + (w >> 1);     // wave-uniform grid-y of its rows
    const size_t tqbase = (size_t)bh * NB_ * 1024;
    const int arow0 = (bh << 10) + i0;

    // ---- persistent Q fragments (wave rows w*16+lh15) ----
    mfrag qAh[2], qAl[2];
#pragma unroll
    for (int ks = 0; ks < 2; ++ks) {
        const size_t qa = (((size_t)(bh << 10) + i0 + w * 16 + lh15) << 6) + (ln4 << 3) + (ks << 5);
        qAh[ks] = *(const mfrag*)&qh_g[qa];
        qAl[ks] = *(const mfrag*)&ql_g[qa];
    }

    // ---- chunk-invariant bucket-x: bxp[jhalf][r] = lutf(xi - xj) ----
    int bxp[2][4];
#pragma unroll
    for (int jh = 0; jh < 2; ++jh)
#pragma unroll
        for (int r = 0; r < 4; ++r) {
            const int xi = (w & 1) * 16 + ln4 * 4 + r;
            bxp[jh][r] = lutf(xi - (jh * 16 + lh15));
        }

    // ---- prefetch regs for chunk 0 ----
    mfrag kstg[4], vstg[2];
#pragma unroll
    for (int rep = 0; rep < 2; ++rep) {
        const int unit = rep * 256 + t;
        const int row = unit >> 3, un = unit & 7;
        const size_t ka = (((size_t)(bh << 10) + row) << 6) + un * 8;
        kstg[rep * 2] = *(const mfrag*)&kh_g[ka];
        kstg[rep * 2 + 1] = *(const mfrag*)&kl_g[ka];
        vstg[rep] = *(const mfrag*)&vth_g[(((size_t)(bh * 64) + row) << 10) + un * 8];
    }
    f32x4 tqpre[4];
#pragma unroll
    for (int p = 0; p < 3; ++p) {
        const int unit = p * 256 + t, u = unit >> 4, j4 = unit & 15;
        tqpre[p] = *(const f32x4*)&tqT[tqbase + ((size_t)u << 10) + (j4 << 2)];
    }
    if (t < 16) tqpre[3] = *(const f32x4*)&tqT[tqbase + ((size_t)48 << 10) + (t << 2)];

    // ---- tks -> LDS bf16 (once) ----
    {
        const size_t tkb = ((size_t)(bh << 10) + i0) * NB_;
        for (int idx = t; idx < 64 * NB_; idx += 256) {
            const int row = idx / NB_, u = idx - row * NB_;
            tks_s[row * 50 + u] = f2bf(tk[tkb + idx]);
        }
    }

    f32x4 apv[4] = {{0.f, 0.f, 0.f, 0.f}, {0.f, 0.f, 0.f, 0.f},
                    {0.f, 0.f, 0.f, 0.f}, {0.f, 0.f, 0.f, 0.f}};
    float srow[4] = {0.f, 0.f, 0.f, 0.f};

#pragma unroll 1
    for (int ch = 0; ch < 16; ++ch) {
        const int jc0 = ch << 6;

        // ---- stage K/V/tq from regs -> LDS ----
#pragma unroll
        for (int rep = 0; rep < 2; ++rep) {
            const int unit = rep * 256 + t;
            const int row = unit >> 3, un = unit & 7;
            const int ldso = row * 128 + ((un ^ (row & 7)) << 4);
            *(mfrag*)((char*)kAh + ldso) = kstg[rep * 2];
            *(mfrag*)((char*)kAl + ldso) = kstg[rep * 2 + 1];
            *(mfrag*)((char*)vAh + ldso) = vstg[rep];
        }
#pragma unroll
        for (int p = 0; p < 3; ++p) {
            const int unit = p * 256 + t, u = unit >> 4, j4 = unit & 15;
            *(f32x4*)&tq_s[u * 68 + (j4 << 2)] = tqpre[p];
        }
        if (t < 16) *(f32x4*)&tq_s[48 * 68 + (t << 2)] = tqpre[3];
        __syncthreads();   // B1: stage visible (loads were issued a chunk ago)

        // ---- QK (bf16x3): all 4 j-tiles for this wave's 16 rows ----
        f32x4 aq[4];
        __builtin_amdgcn_s_setprio(1);
#pragma unroll
        for (int ji = 0; ji < 4; ++ji) {
            const int rb = ji * 16 + lh15, swb = rb & 7;
            const mfrag bh0 = *(const mfrag*)((const char*)kAh + rb * 128 + ((ln4 ^ swb) << 4));
            const mfrag bl0 = *(const mfrag*)((const char*)kAl + rb * 128 + ((ln4 ^ swb) << 4));
            const mfrag bh1 = *(const mfrag*)((const char*)kAh + rb * 128 + (((4 + ln4) ^ swb) << 4));
            const mfrag bl1 = *(const mfrag*)((const char*)kAl + rb * 128 + (((4 + ln4) ^ swb) << 4));
            f32x4 c = {0.f, 0.f, 0.f, 0.f};
            c = __builtin_amdgcn_mfma_f32_16x16x32_bf16(qAh[0], bh0, c, 0, 0, 0);
            c = __builtin_amdgcn_mfma_f32_16x16x32_bf16(qAh[0], bl0, c, 0, 0, 0);
            c = __builtin_amdgcn_mfma_f32_16x16x32_bf16(qAl[0], bh0, c, 0, 0, 0);
            c = __builtin_amdgcn_mfma_f32_16x16x32_bf16(qAh[1], bh1, c, 0, 0, 0);
            c = __builtin_amdgcn_mfma_f32_16x16x32_bf16(qAh[1], bl1, c, 0, 0, 0);
            c = __builtin_amdgcn_mfma_f32_16x16x32_bf16(qAl[1], bh1, c, 0, 0, 0);
            aq[ji] = c;
        }
        __builtin_amdgcn_s_setprio(0);

        // ---- issue prefetch for ch+1 (drains at B2, after full compute) ----
        if (ch < 15) {
            const int jc1 = jc0 + 64;
#pragma unroll
            for (int rep = 0; rep < 2; ++rep) {
                const int unit = rep * 256 + t;
                const int row = unit >> 3, un = unit & 7;
                const size_t ka = (((size_t)(bh << 10) + jc1 + row) << 6) + un * 8;
                kstg[rep * 2] = *(const mfrag*)&kh_g[ka];
                kstg[rep * 2 + 1] = *(const mfrag*)&kl_g[ka];
                vstg[rep] = *(const mfrag*)&vth_g[(((size_t)(bh * 64) + row) << 10) + jc1 + un * 8];
            }
#pragma unroll
            for (int p = 0; p < 3; ++p) {
                const int unit = p * 256 + t, u = unit >> 4, j4 = unit & 15;
                tqpre[p] = *(const f32x4*)&tqT[tqbase + ((size_t)u << 10) + jc1 + (j4 << 2)];
            }
            if (t < 16) tqpre[3] = *(const f32x4*)&tqT[tqbase + ((size_t)48 << 10) + jc1 + (t << 2)];
        }

        // ---- bias + exp + emit (wave-local aw rows; P bf16-only) ----
#pragma unroll
        for (int ji = 0; ji < 4; ++ji) {
            const int yj = (ch << 1) + (ji >> 1);
            const int by7 = 7 * lutf(yi - yj);
            const int jl = ji * 16 + lh15;
#pragma unroll
            for (int r = 0; r < 4; ++r) {
                const int il = w * 16 + ln4 * 4 + r;
                const int bij = by7 + bxp[ji & 1][r];
                const float e = __expf(fmaf(aq[ji][r], SCALE_,
                                            bf2f(tks_s[il * 50 + bij]) + tq_s[(48 - bij) * 68 + jl]));
                srow[r] += e;
                attn[((size_t)(arow0 + il) << 10) + jc0 + jl] = e;
                const int off = il * 128 + ((jl << 1) ^ ((il & 7) << 4));
                *(u16*)((char*)awh + off) = f2bf(e);
            }
        }
        // wave-local aw: compiler inserts lgkmcnt wait before PV reads

        // ---- PV (bf16): P from own aw rows, V(hi) from vA LDS ----
        {
            const int rowA = w * 16 + lh15, sa = (rowA & 7) << 4;
            mfrag pah[2];
#pragma unroll
            for (int ks = 0; ks < 2; ++ks)
                pah[ks] = *(const mfrag*)((const char*)awh + rowA * 128 + ((((ln4 << 4) + (ks << 6))) ^ sa));
            __builtin_amdgcn_s_setprio(1);
#pragma unroll
            for (int di = 0; di < 4; ++di) {
                const int rv = di * 16 + lh15, swv = rv & 7;
                const mfrag vh0 = *(const mfrag*)((const char*)vAh + rv * 128 + ((ln4 ^ swv) << 4));
                const mfrag vh1 = *(const mfrag*)((const char*)vAh + rv * 128 + (((4 + ln4) ^ swv) << 4));
                f32x4 c = apv[di];
                c = __builtin_amdgcn_mfma_f32_16x16x32_bf16(pah[0], vh0, c, 0, 0, 0);
                c = __builtin_amdgcn_mfma_f32_16x16x32_bf16(pah[1], vh1, c, 0, 0, 0);
                apv[di] = c;
            }
            __builtin_amdgcn_s_setprio(0);
        }
        __syncthreads();   // B2: all LDS reads done; prefetch/stores drained
    }

    // ---- epilogue: row sums (butterfly over 16 lanes sharing a row) ----
    float inv[4];
#pragma unroll
    for (int r = 0; r < 4; ++r) {
        float s = srow[r];
        s += __shfl_xor(s, 1); s += __shfl_xor(s, 2);
        s += __shfl_xor(s, 4); s += __shfl_xor(s, 8);
        inv[r] = 1.0f / s;
        if (lh15 == 0) s_arr[((size_t)bh << 10) + i0 + w * 16 + ln4 * 4 + r] = s;
    }

    // ---- normalize + write pre (rpe_v added later from bs) ----
#pragma unroll
    for (int di = 0; di < 4; ++di) {
        const int d = di * 16 + lh15;
#pragma unroll
        for (int r = 0; r < 4; ++r) {
            const int i = i0 + w * 16 + ln4 * 4 + r;
            pre[((size_t)(b * N_ + i)) * C_ + h * HD_ + d] = apv[di][r] * inv[r];
        }
    }
}

// ---------------------------------------------------------------------------
// K4: rescale attn rows by 1/rowsum AND compute bucket sums bs[bh][i][49].
// ---------------------------------------------------------------------------
__global__ void irpe_rescale_bucket_k(float* __restrict__ attn, const float* __restrict__ s_arr,
                                      float* __restrict__ bs) {
    __shared__ float R[4][32][8];    // 4 KB
    __shared__ float inv_s[4];
    const int bh = blockIdx.y;
    const int i0 = blockIdx.x * 4;
    const int t = threadIdx.x;
    const int r = t >> 6, lane = t & 63;
    const int i = i0 + r, xi = i & 31;
    const float inv = 1.0f / s_arr[((size_t)bh << 10) + i];
    if (lane == 0) inv_s[r] = inv;
    for (int idx = t; idx < 4 * 32 * 8; idx += 256) ((float*)R)[idx] = 0.f;
    __syncthreads();

    const int j0 = lane * 16;
    const int yj = j0 >> 5;
    float4* rowp = (float4*)&attn[((size_t)((bh << 10) + i)) << 10];
    float4 xv0 = rowp[(j0 >> 2) + 0], xv1 = rowp[(j0 >> 2) + 1];
    float4 xv2 = rowp[(j0 >> 2) + 2], xv3 = rowp[(j0 >> 2) + 3];

    float acc = 0.f;
    int cur = lutf(xi - (j0 & 31));
#define STEP_(val, xjc) { const int bx_ = lutf(xi - (xjc));                         \
        if (bx_ != cur) { atomicAdd(&R[r][yj][cur], acc); acc = 0.f; cur = bx_; }   \
        acc += (val); }
    const int xb = j0 & 31;
    STEP_(xv0.x, xb + 0)  STEP_(xv0.y, xb + 1)  STEP_(xv0.z, xb + 2)  STEP_(xv0.w, xb + 3)
    STEP_(xv1.x, xb + 4)  STEP_(xv1.y, xb + 5)  STEP_(xv1.z, xb + 6)  STEP_(xv1.w, xb + 7)
    STEP_(xv2.x, xb + 8)  STEP_(xv2.y, xb + 9)  STEP_(xv2.z, xb + 10) STEP_(xv2.w, xb + 11)
    STEP_(xv3.x, xb + 12) STEP_(xv3.y, xb + 13) STEP_(xv3.z, xb + 14) STEP_(xv3.w, xb + 15)
    atomicAdd(&R[r][yj][cur], acc);
#undef STEP_

    xv0.x *= inv; xv0.y *= inv; xv0.z *= inv; xv0.w *= inv;
    xv1.x *= inv; xv1.y *= inv; xv1.z *= inv; xv1.w *= inv;
    xv2.x *= inv; xv2.y *= inv; xv2.z *= inv; xv2.w *= inv;
    xv3.x *= inv; xv3.y *= inv; xv3.z *= inv; xv3.w *= inv;
    rowp[(j0 >> 2) + 0] = xv0; rowp[(j0 >> 2) + 1] = xv1;
    rowp[(j0 >> 2) + 2] = xv2; rowp[(j0 >> 2) + 3] = xv3;
    __syncthreads();

    if (t < 4 * NB_) {
        const int rr = t / NB_, u = t - rr * NB_;
        const int by = u / 7, bx = u - by * 7;
        const int yi2 = (i0 + rr) >> 5;
        float s = 0.f;
#pragma unroll
        for (int yj2 = 0; yj2 < 32; ++yj2)
            if (lutf(yi2 - yj2) == by) s += R[rr][yj2][bx];
        bs[((size_t)((bh << 10) + i0 + rr)) * NB_ + u] = s * inv_s[rr];
    }
}

// ---------------------------------------------------------------------------
// K4b: pre += bs @ w_rpe_v
// ---------------------------------------------------------------------------
__global__ void irpe_addpre_k(const float* __restrict__ bs, const float* __restrict__ w_rpe_v,
                              float* __restrict__ pre) {
    __shared__ float wv[NB_ * 64];
    __shared__ float bss[16 * 52];
    const int bh = blockIdx.y, b = bh / H_, h = bh % H_;
    const int i0 = blockIdx.x * 16;
    const int t = threadIdx.x;
    for (int idx = t; idx < NB_ * 64; idx += 256) wv[idx] = w_rpe_v[idx];
    for (int idx = t; idx < 16 * NB_; idx += 256) {
        const int il = idx / NB_, u = idx - il * NB_;
        bss[il * 52 + u] = bs[((size_t)((bh << 10) + i0 + il)) * NB_ + u];
    }
    __syncthreads();
    const int il = t >> 4, d4 = (t & 15) * 4;
    f32x4 acc = {0.f, 0.f, 0.f, 0.f};
    for (int u = 0; u < NB_; ++u) {
        const float bv = bss[il * 52 + u];
        const f32x4 wvv = *(const f32x4*)&wv[u * 64 + d4];
        acc += bv * wvv;
    }
    float* p = &pre[((size_t)(b * N_ + i0 + il)) * C_ + h * HD_ + d4];
    f32x4 old = *(const f32x4*)p;
    *(f32x4*)p = old + acc;
}

// ---------------------------------------------------------------------------
// K5: projection GEMM via bf16x3 MFMA: out[m,n] = pre[m,:] . W[n,:] + b[n]
// M=8192, N=768, K=768. Block 64x64, 4 waves, K-step 64.
// ---------------------------------------------------------------------------
__global__ __launch_bounds__(256, 4) void irpe_proj_mfma_k(
    const float* __restrict__ A, const float* __restrict__ Bw,
    const float* __restrict__ bias, float* __restrict__ Cout) {
    __shared__ u16 Ah[4096], Al[4096], Bh[4096], Bl[4096];   // 32 KB
    const int bm = blockIdx.x * 64, bn = blockIdx.y * 64;
    const int t = threadIdx.x;
    const int w = t >> 6, lane = t & 63;
    const int ln4 = lane >> 4, lh15 = lane & 15;

    f32x4 acc[4] = {{0.f, 0.f, 0.f, 0.f}, {0.f, 0.f, 0.f, 0.f},
                    {0.f, 0.f, 0.f, 0.f}, {0.f, 0.f, 0.f, 0.f}};
    float bias_r[4];
#pragma unroll
    for (int ji = 0; ji < 4; ++ji) bias_r[ji] = bias[bn + ji * 16 + lh15];

    const int srow_ = t >> 3, sun = t & 7;          // staging: 32 rows/rep
    const int ldso = srow_ * 128 + ((sun ^ (srow_ & 7)) << 4);

    for (int kt = 0; kt < C_; kt += 64) {
#pragma unroll
        for (int rep = 0; rep < 2; ++rep) {
            const int row = rep * 32 + srow_;
            const int ldo = ldso + rep * 32 * 128;
            const float* ap = &A[(size_t)(bm + row) * C_ + kt + sun * 8];
            const float* bp = &Bw[(size_t)(bn + row) * C_ + kt + sun * 8];
            const float4 a0 = *(const float4*)ap, a1 = *(const float4*)(ap + 4);
            const float4 b0 = *(const float4*)bp, b1 = *(const float4*)(bp + 4);
            const float av[8] = {a0.x, a0.y, a0.z, a0.w, a1.x, a1.y, a1.z, a1.w};
            const float bv[8] = {b0.x, b0.y, b0.z, b0.w, b1.x, b1.y, b1.z, b1.w};
            u32 ahh[4], all_[4], bhh[4], bll[4];
#pragma unroll
            for (int jj = 0; jj < 4; ++jj) {
                const u16 h0 = f2bf(av[jj * 2]), h1 = f2bf(av[jj * 2 + 1]);
                ahh[jj] = (u32)h0 | ((u32)h1 << 16);
                all_[jj] = (u32)f2bf(av[jj * 2] - bf2f(h0)) | ((u32)f2bf(av[jj * 2 + 1] - bf2f(h1)) << 16);
                const u16 g0 = f2bf(bv[jj * 2]), g1 = f2bf(bv[jj * 2 + 1]);
                bhh[jj] = (u32)g0 | ((u32)g1 << 16);
                bll[jj] = (u32)f2bf(bv[jj * 2] - bf2f(g0)) | ((u32)f2bf(bv[jj * 2 + 1] - bf2f(g1)) << 16);
            }
            *(uint4*)((char*)Ah + ldo) = make_uint4(ahh[0], ahh[1], ahh[2], ahh[3]);
            *(uint4*)((char*)Al + ldo) = make_uint4(all_[0], all_[1], all_[2], all_[3]);
            *(uint4*)((char*)Bh + ldo) = make_uint4(bhh[0], bhh[1], bhh[2], bhh[3]);
            *(uint4*)((char*)Bl + ldo) = make_uint4(bll[0], bll[1], bll[2], bll[3]);
        }
        __syncthreads();

        const int ra = w * 16 + lh15, sa = ra & 7;
        const mfrag aF0h = *(const mfrag*)((const char*)Ah + ra * 128 + ((ln4 ^ sa) << 4));
        const mfrag aF0l = *(const mfrag*)((const char*)Al + ra * 128 + ((ln4 ^ sa) << 4));
        const mfrag aF1h = *(const mfrag*)((const char*)Ah + ra * 128 + (((4 + ln4) ^ sa) << 4));
        const mfrag aF1l = *(const mfrag*)((const char*)Al + ra * 128 + (((4 + ln4) ^ sa) << 4));
#pragma unroll
        for (int ji = 0; ji < 4; ++ji) {
            const int rb = ji * 16 + lh15, sb = rb & 7;
            const mfrag bF0h = *(const mfrag*)((const char*)Bh + rb * 128 + ((ln4 ^ sb) << 4));
            const mfrag bF0l = *(const mfrag*)((const char*)Bl + rb * 128 + ((ln4 ^ sb) << 4));
            const mfrag bF1h = *(const mfrag*)((const char*)Bh + rb * 128 + (((4 + ln4) ^ sb) << 4));
            const mfrag bF1l = *(const mfrag*)((const char*)Bl + rb * 128 + (((4 + ln4) ^ sb) << 4));
            f32x4 c = acc[ji];
            c = __builtin_amdgcn_mfma_f32_16x16x32_bf16(aF0h, bF0h, c, 0, 0, 0);
            c = __builtin_amdgcn_mfma_f32_16x16x32_bf16(aF0h, bF0l, c, 0, 0, 0);
            c = __builtin_amdgcn_mfma_f32_16x16x32_bf16(aF0l, bF0h, c, 0, 0, 0);
            c = __builtin_amdgcn_mfma_f32_16x16x32_bf16(aF1h, bF1h, c, 0, 0, 0);
            c = __builtin_amdgcn_mfma_f32_16x16x32_bf16(aF1h, bF1l, c, 0, 0, 0);
            c = __builtin_amdgcn_mfma_f32_16x16x32_bf16(aF1l, bF1h, c, 0, 0, 0);
            acc[ji] = c;
        }
        __syncthreads();
    }

#pragma unroll
    for (int ji = 0; ji < 4; ++ji) {
        const int col = bn + ji * 16 + lh15;
#pragma unroll
        for (int r = 0; r < 4; ++r) {
            const int row = bm + w * 16 + ln4 * 4 + r;
            Cout[(size_t)row * C_ + col] = acc[ji][r] + bias_r[ji];
        }
    }
}

// ---------------------------------------------------------------------------
extern "C" void kernel_launch(void* const* d_in, const int* in_sizes, int n_in,
                              void* d_out, int out_size, void* d_ws, size_t ws_size,
                              hipStream_t stream) {
    const float* q       = (const float*)d_in[0];
    const float* k       = (const float*)d_in[1];
    const float* v       = (const float*)d_in[2];
    const float* w_rpe_q = (const float*)d_in[3];
    const float* w_rpe_k = (const float*)d_in[4];
    const float* w_rpe_v = (const float*)d_in[5];
    const float* proj_w  = (const float*)d_in[6];
    const float* proj_b  = (const float*)d_in[7];

    float* out  = (float*)d_out;               // [B,N,C]
    float* attn = out + (size_t)B_ * N_ * C_;  // [B,H,N,N]

    char* ws = (char*)d_ws;
    float* tk    = (float*)ws; ws += (size_t)BH_ * N_ * NB_ * 4;
    float* tqT   = (float*)ws; ws += (size_t)BH_ * NB_ * N_ * 4;
    float* pre   = (float*)ws; ws += (size_t)B_ * N_ * C_ * 4;
    float* s_arr = (float*)ws; ws += (size_t)BH_ * N_ * 4;
    float* bs    = (float*)ws; ws += (size_t)BH_ * N_ * NB_ * 4;
    u16* qh  = (u16*)ws; ws += (size_t)BH_ * N_ * 64 * 2;
    u16* ql  = (u16*)ws; ws += (size_t)BH_ * N_ * 64 * 2;
    u16* kh  = (u16*)ws; ws += (size_t)BH_ * N_ * 64 * 2;
    u16* kl  = (u16*)ws; ws += (size_t)BH_ * N_ * 64 * 2;
    u16* vth = (u16*)ws; ws += (size_t)BH_ * 64 * N_ * 2;

    irpe_prep_k<<<dim3(N_ / 4, BH_), 256, 0, stream>>>(q, k, w_rpe_q, w_rpe_k,
                                                       qh, ql, kh, kl, tk, tqT);
    irpe_vt_k<<<dim3(16, BH_), 256, 0, stream>>>(v, vth);

    irpe_attn_mfma_k<<<BH_ * (N_ / 64), 256, 0, stream>>>(
        qh, ql, kh, kl, vth, tk, tqT, attn, s_arr, pre);

    irpe_rescale_bucket_k<<<dim3(N_ / 4, BH_), 256, 0, stream>>>(attn, s_arr, bs);
    irpe_addpre_k<<<dim3(N_ / 16, BH_), 256, 0, stream>>>(bs, w_rpe_v, pre);
    irpe_proj_mfma_k<<<dim3((B_ * N_) / 64, C_ / 64), 256, 0, stream>>>(pre, proj_w, proj_b, out);
}

// Round 10
// 770.691 us; speedup vs baseline: 1.0010x; 1.0010x over previous
//
#include <hip/hip_runtime.h>

#define B_ 8
#define N_ 1024
#define C_ 768
#define H_ 12
#define HD_ 64
#define NB_ 49
#define BH_ 96
#define SCALE_ 0.125f

typedef unsigned int u32;
typedef unsigned short u16;
typedef __attribute__((ext_vector_type(8))) short mfrag;   // 8 bf16 (4 VGPRs)
typedef __attribute__((ext_vector_type(4))) float f32x4;
typedef __attribute__((ext_vector_type(4))) u32 u32x4;

__device__ __forceinline__ u16 f2bf(float x) {             // f32 -> bf16 (RNE)
    u32 u = __float_as_uint(x);
    u32 r = u + 0x7FFFu + ((u >> 16) & 1u);
    return (u16)(r >> 16);
}
__device__ __forceinline__ float bf2f(u16 h) { return __uint_as_float(((u32)h) << 16); }

// iRPE piecewise bucket (closed form for ALPHA=1.9, BETA=3.8, GAMMA=15.2):
// |d|: 0->0, 1->1, 2,3->2, >=4->3 ; bucket = 3 + sign(d)*g  (in [0,6])
__device__ __forceinline__ int lutf(int d) {
    int a = d < 0 ? -d : d;
    int gg = (a < 2 ? a : 2) + (a >= 4 ? 1 : 0);
    return d < 0 ? 3 - gg : 3 + gg;
}

// ---------------------------------------------------------------------------
// K1 (fused prep): q,k bf16 hi/lo buffers; tk f32 [bh][i][49];
// tqT bf16 [bh][49][1024] (pre-scaled).
// ---------------------------------------------------------------------------
__global__ void irpe_prep_k(const float* __restrict__ q, const float* __restrict__ k,
                            const float* __restrict__ w_rpe_q, const float* __restrict__ w_rpe_k,
                            u16* __restrict__ qh, u16* __restrict__ ql,
                            u16* __restrict__ kh, u16* __restrict__ kl,
                            float* __restrict__ tk, u16* __restrict__ tqT) {
    const int bh = blockIdx.y, b = bh / H_, h = bh % H_;
    const int row0 = blockIdx.x * 4;
    __shared__ float qs[4][HD_], ks[4][HD_];
    const int t = threadIdx.x;
    {
        const int r = t >> 6, d = t & 63;
        const size_t gi = ((size_t)(b * N_ + row0 + r)) * C_ + h * HD_ + d;
        const float vq = q[gi], vk = k[gi];
        qs[r][d] = vq;
        ks[r][d] = vk;
        const size_t so = (((size_t)(bh << 10)) + row0 + r) * 64 + d;
        const u16 qhi = f2bf(vq), khi = f2bf(vk);
        qh[so] = qhi; ql[so] = f2bf(vq - bf2f(qhi));
        kh[so] = khi; kl[so] = f2bf(vk - bf2f(khi));
    }
    __syncthreads();
    if (t < 4 * NB_) {
        const int r = t / NB_, u = t - r * NB_;
        float dk = 0.f, dq = 0.f;
#pragma unroll
        for (int d = 0; d < HD_; ++d) {
            dk = fmaf(qs[r][d], w_rpe_k[d * NB_ + u], dk);
            dq = fmaf(ks[r][d], w_rpe_q[d * NB_ + u], dq);
        }
        tk[((size_t)bh * N_ + row0 + r) * NB_ + u] = dk;
        tqT[(((size_t)bh * NB_ + u) << 10) + row0 + r] = f2bf(dq * SCALE_);
    }
}

// ---------------------------------------------------------------------------
// K0b: v -> transposed bf16 (hi only) [bh][64(d)][1024(j)]
// ---------------------------------------------------------------------------
__global__ void irpe_vt_k(const float* __restrict__ v, u16* __restrict__ vth) {
    __shared__ float tile[64][65];
    const int bh = blockIdx.y, jc0 = blockIdx.x * 64;
    const int b = bh / H_, h = bh % H_;
    const int t = threadIdx.x;
#pragma unroll
    for (int rep = 0; rep < 4; ++rep) {
        const int fl = rep * 256 + t;
        const int jr = fl >> 4, c4 = (fl & 15) * 4;
        const float4 x = *(const float4*)&v[((size_t)(b * N_ + jc0 + jr)) * C_ + h * HD_ + c4];
        tile[jr][c4] = x.x; tile[jr][c4 + 1] = x.y; tile[jr][c4 + 2] = x.z; tile[jr][c4 + 3] = x.w;
    }
    __syncthreads();
    const int d = t >> 2, jq = (t & 3) * 16;
    u32 ph[8];
#pragma unroll
    for (int jj = 0; jj < 8; ++jj) {
        const u16 h0 = f2bf(tile[jq + jj * 2][d]);
        const u16 h1 = f2bf(tile[jq + jj * 2 + 1][d]);
        ph[jj] = (u32)h0 | ((u32)h1 << 16);
    }
    const size_t dst = (((size_t)bh * 64 + d) << 10) + jc0 + jq;
    *(uint4*)&vth[dst] = make_uint4(ph[0], ph[1], ph[2], ph[3]);
    *(uint4*)&vth[dst + 8] = make_uint4(ph[4], ph[5], ph[6], ph[7]);
}

// ---------------------------------------------------------------------------
// K_main: single-sweep fused attention, bf16x3 QK / bf16 PV, wave-local P.
// Block = (bh, 64 i-rows), XCD-pinned. 4 waves; wave w owns rows w*16..+15.
// 2 barriers/chunk. e (unnormalized, bf16) is stored IN-PLACE into the attn
// f32 buffer (first 2KB of each 4KB row) via batched nt stores from awh LDS;
// rescale kernel expands/normalizes. LDS ~45 KB -> 3 blocks/CU.
// ---------------------------------------------------------------------------
__global__ __launch_bounds__(256, 3) void irpe_attn_mfma_k(
    const u16* __restrict__ qh_g, const u16* __restrict__ ql_g,
    const u16* __restrict__ kh_g, const u16* __restrict__ kl_g,
    const u16* __restrict__ vth_g,
    const float* __restrict__ tk, const u16* __restrict__ tqT,
    u16* __restrict__ e_g, float* __restrict__ s_arr, float* __restrict__ pre) {
    __shared__ u16 kAh[4096], kAl[4096];     // K  [64 j][64 d] swizzled  16 KB
    __shared__ u16 vAh[4096];                // vT [64 d][64 j] swizzled   8 KB
    __shared__ u16 awh[4096];                // P  [64 i][64 j] swizzled   8 KB
    __shared__ u16 tq_su[NB_ * 72];          // [49][72] bf16             6.9 KB
    __shared__ u16 tks_s[64 * 50];           // [64][50] bf16            6.25 KB

    const int gid = blockIdx.x;
    const int xcd = gid & 7, L = gid >> 3;
    const int bh = xcd * 12 + (L >> 4);      // 12 bh per XCD, itile-inner
    const int itile = L & 15;
    const int b = bh / H_, h = bh % H_;
    const int i0 = itile * 64;
    const int t = threadIdx.x;
    const int w = t >> 6, lane = t & 63;
    const int ln4 = lane >> 4, lh15 = lane & 15;
    const int yi = itile * 2 + (w >> 1);     // wave-uniform grid-y of its rows
    const size_t tqbase = (size_t)bh * NB_ * 1024;
    const int arow0 = (bh << 10) + i0;

    // ---- persistent Q fragments ----
    mfrag qAh[2], qAl[2];
#pragma unroll
    for (int ks = 0; ks < 2; ++ks) {
        const size_t qa = (((size_t)(bh << 10) + i0 + w * 16 + lh15) << 6) + (ln4 << 3) + (ks << 5);
        qAh[ks] = *(const mfrag*)&qh_g[qa];
        qAl[ks] = *(const mfrag*)&ql_g[qa];
    }

    // ---- chunk-invariant bucket-x ----
    int bxp[2][4];
#pragma unroll
    for (int jh = 0; jh < 2; ++jh)
#pragma unroll
        for (int r = 0; r < 4; ++r) {
            const int xi = (w & 1) * 16 + ln4 * 4 + r;
            bxp[jh][r] = lutf(xi - (jh * 16 + lh15));
        }

    // ---- prefetch regs for chunk 0 ----
    mfrag kstg[4], vstg[2];
#pragma unroll
    for (int rep = 0; rep < 2; ++rep) {
        const int unit = rep * 256 + t;
        const int row = unit >> 3, un = unit & 7;
        const size_t ka = (((size_t)(bh << 10) + row) << 6) + un * 8;
        kstg[rep * 2] = *(const mfrag*)&kh_g[ka];
        kstg[rep * 2 + 1] = *(const mfrag*)&kl_g[ka];
        vstg[rep] = *(const mfrag*)&vth_g[(((size_t)(bh * 64) + row) << 10) + un * 8];
    }
    u32x4 tqpre[2];
    {
        const int u0 = t >> 3, c0 = t & 7;
        tqpre[0] = *(const u32x4*)&tqT[tqbase + ((size_t)u0 << 10) + c0 * 8];
        if (t < 136) {
            const int u1 = (256 + t) >> 3, c1 = t & 7;
            tqpre[1] = *(const u32x4*)&tqT[tqbase + ((size_t)u1 << 10) + c1 * 8];
        }
    }

    // ---- tks -> LDS bf16 (once) ----
    {
        const size_t tkb = ((size_t)(bh << 10) + i0) * NB_;
        for (int idx = t; idx < 64 * NB_; idx += 256) {
            const int row = idx / NB_, u = idx - row * NB_;
            tks_s[row * 50 + u] = f2bf(tk[tkb + idx]);
        }
    }

    f32x4 apv[4] = {{0.f, 0.f, 0.f, 0.f}, {0.f, 0.f, 0.f, 0.f},
                    {0.f, 0.f, 0.f, 0.f}, {0.f, 0.f, 0.f, 0.f}};
    float srow[4] = {0.f, 0.f, 0.f, 0.f};

#pragma unroll 1
    for (int ch = 0; ch < 16; ++ch) {
        const int jc0 = ch << 6;

        // ---- stage K/V/tq from regs -> LDS ----
#pragma unroll
        for (int rep = 0; rep < 2; ++rep) {
            const int unit = rep * 256 + t;
            const int row = unit >> 3, un = unit & 7;
            const int ldso = row * 128 + ((un ^ (row & 7)) << 4);
            *(mfrag*)((char*)kAh + ldso) = kstg[rep * 2];
            *(mfrag*)((char*)kAl + ldso) = kstg[rep * 2 + 1];
            *(mfrag*)((char*)vAh + ldso) = vstg[rep];
        }
        {
            const int u0 = t >> 3, c0 = t & 7;
            *(u32x4*)((char*)tq_su + u0 * 144 + c0 * 16) = tqpre[0];
            if (t < 136) {
                const int u1 = (256 + t) >> 3;
                *(u32x4*)((char*)tq_su + u1 * 144 + (t & 7) * 16) = tqpre[1];
            }
        }
        __syncthreads();   // B1: stage visible (loads issued a chunk ago)

        // ---- QK (bf16x3) ----
        f32x4 aq[4];
        __builtin_amdgcn_s_setprio(1);
#pragma unroll
        for (int ji = 0; ji < 4; ++ji) {
            const int rb = ji * 16 + lh15, swb = rb & 7;
            const mfrag bh0 = *(const mfrag*)((const char*)kAh + rb * 128 + ((ln4 ^ swb) << 4));
            const mfrag bl0 = *(const mfrag*)((const char*)kAl + rb * 128 + ((ln4 ^ swb) << 4));
            const mfrag bh1 = *(const mfrag*)((const char*)kAh + rb * 128 + (((4 + ln4) ^ swb) << 4));
            const mfrag bl1 = *(const mfrag*)((const char*)kAl + rb * 128 + (((4 + ln4) ^ swb) << 4));
            f32x4 c = {0.f, 0.f, 0.f, 0.f};
            c = __builtin_amdgcn_mfma_f32_16x16x32_bf16(qAh[0], bh0, c, 0, 0, 0);
            c = __builtin_amdgcn_mfma_f32_16x16x32_bf16(qAh[0], bl0, c, 0, 0, 0);
            c = __builtin_amdgcn_mfma_f32_16x16x32_bf16(qAl[0], bh0, c, 0, 0, 0);
            c = __builtin_amdgcn_mfma_f32_16x16x32_bf16(qAh[1], bh1, c, 0, 0, 0);
            c = __builtin_amdgcn_mfma_f32_16x16x32_bf16(qAh[1], bl1, c, 0, 0, 0);
            c = __builtin_amdgcn_mfma_f32_16x16x32_bf16(qAl[1], bh1, c, 0, 0, 0);
            aq[ji] = c;
        }
        __builtin_amdgcn_s_setprio(0);

        // ---- issue prefetch for ch+1 ----
        if (ch < 15) {
            const int jc1 = jc0 + 64;
#pragma unroll
            for (int rep = 0; rep < 2; ++rep) {
                const int unit = rep * 256 + t;
                const int row = unit >> 3, un = unit & 7;
                const size_t ka = (((size_t)(bh << 10) + jc1 + row) << 6) + un * 8;
                kstg[rep * 2] = *(const mfrag*)&kh_g[ka];
                kstg[rep * 2 + 1] = *(const mfrag*)&kl_g[ka];
                vstg[rep] = *(const mfrag*)&vth_g[(((size_t)(bh * 64) + row) << 10) + jc1 + un * 8];
            }
            const int u0 = t >> 3, c0 = t & 7;
            tqpre[0] = *(const u32x4*)&tqT[tqbase + ((size_t)u0 << 10) + jc1 + c0 * 8];
            if (t < 136) {
                const int u1 = (256 + t) >> 3;
                tqpre[1] = *(const u32x4*)&tqT[tqbase + ((size_t)u1 << 10) + jc1 + (t & 7) * 8];
            }
        }

        // ---- bias + exp -> awh (wave-local; no global store here) ----
#pragma unroll
        for (int ji = 0; ji < 4; ++ji) {
            const int yj = (ch << 1) + (ji >> 1);
            const int by7 = 7 * lutf(yi - yj);
            const int jl = ji * 16 + lh15;
#pragma unroll
            for (int r = 0; r < 4; ++r) {
                const int il = w * 16 + ln4 * 4 + r;
                const int bij = by7 + bxp[ji & 1][r];
                const float e = __expf(fmaf(aq[ji][r], SCALE_,
                                            bf2f(tks_s[il * 50 + bij]) + bf2f(tq_su[(48 - bij) * 72 + jl])));
                srow[r] += e;
                const int off = il * 128 + ((jl << 1) ^ ((il & 7) << 4));
                *(u16*)((char*)awh + off) = f2bf(e);
            }
        }
        // wave-local aw: compiler inserts lgkmcnt wait before PV reads

        // ---- PV (bf16) ----
        {
            const int rowA = w * 16 + lh15, sa = (rowA & 7) << 4;
            mfrag pah[2];
#pragma unroll
            for (int ks = 0; ks < 2; ++ks)
                pah[ks] = *(const mfrag*)((const char*)awh + rowA * 128 + ((((ln4 << 4) + (ks << 6))) ^ sa));
            __builtin_amdgcn_s_setprio(1);
#pragma unroll
            for (int di = 0; di < 4; ++di) {
                const int rv = di * 16 + lh15, swv = rv & 7;
                const mfrag vh0 = *(const mfrag*)((const char*)vAh + rv * 128 + ((ln4 ^ swv) << 4));
                const mfrag vh1 = *(const mfrag*)((const char*)vAh + rv * 128 + (((4 + ln4) ^ swv) << 4));
                f32x4 c = apv[di];
                c = __builtin_amdgcn_mfma_f32_16x16x32_bf16(pah[0], vh0, c, 0, 0, 0);
                c = __builtin_amdgcn_mfma_f32_16x16x32_bf16(pah[1], vh1, c, 0, 0, 0);
                apv[di] = c;
            }
            __builtin_amdgcn_s_setprio(0);
        }

        // ---- batched e store: own-wave awh rows -> e_g (bf16, nt) ----
#pragma unroll
        for (int rep = 0; rep < 2; ++rep) {
            const int unit = rep * 64 + lane;          // 128 units x 16B = own 2KB
            const int rowl = unit >> 3, un = unit & 7;
            const int row = w * 16 + rowl;
            const u32x4 val = *(const u32x4*)((const char*)awh + row * 128 + ((un << 4) ^ ((row & 7) << 4)));
            __builtin_nontemporal_store(val,
                (u32x4*)&e_g[((size_t)(arow0 + row) << 11) + jc0 + un * 8]);
        }
        __syncthreads();   // B2: LDS reads done; prefetch/stores drained
    }

    // ---- epilogue: row sums ----
    float inv[4];
#pragma unroll
    for (int r = 0; r < 4; ++r) {
        float s = srow[r];
        s += __shfl_xor(s, 1); s += __shfl_xor(s, 2);
        s += __shfl_xor(s, 4); s += __shfl_xor(s, 8);
        inv[r] = 1.0f / s;
        if (lh15 == 0) s_arr[((size_t)bh << 10) + i0 + w * 16 + ln4 * 4 + r] = s;
    }

    // ---- normalize + write pre (rpe_v added later from bs) ----
#pragma unroll
    for (int di = 0; di < 4; ++di) {
        const int d = di * 16 + lh15;
#pragma unroll
        for (int r = 0; r < 4; ++r) {
            const int i = i0 + w * 16 + ln4 * 4 + r;
            pre[((size_t)(b * N_ + i)) * C_ + h * HD_ + d] = apv[di][r] * inv[r];
        }
    }
}

// ---------------------------------------------------------------------------
// K4: expand bf16 e (in-place in attn buffer) -> normalized f32 attn (nt),
// AND compute bucket sums bs[bh][i][49]. Per-row in-place is safe: each wave
// reads its row's e fully into regs before any store of that row.
// ---------------------------------------------------------------------------
__global__ void irpe_rescale_bucket_k(float* __restrict__ attn, const float* __restrict__ s_arr,
                                      float* __restrict__ bs) {
    __shared__ float R[4][32][8];    // 4 KB
    __shared__ float inv_s[4];
    const int bh = blockIdx.y;
    const int i0 = blockIdx.x * 4;
    const int t = threadIdx.x;
    const int r = t >> 6, lane = t & 63;
    const int i = i0 + r, xi = i & 31;
    const float inv = 1.0f / s_arr[((size_t)bh << 10) + i];
    if (lane == 0) inv_s[r] = inv;
    for (int idx = t; idx < 4 * 32 * 8; idx += 256) ((float*)R)[idx] = 0.f;
    __syncthreads();

    const int j0 = lane * 16;
    const int yj = j0 >> 5;
    const u16* erow = (const u16*)attn + (((size_t)((bh << 10) + i)) << 11);
    const u32x4 ea = *(const u32x4*)&erow[j0];
    const u32x4 eb = *(const u32x4*)&erow[j0 + 8];
    float ev[16];
    {
        const u32 wds[8] = {ea.x, ea.y, ea.z, ea.w, eb.x, eb.y, eb.z, eb.w};
#pragma unroll
        for (int m = 0; m < 8; ++m) {
            ev[2 * m] = bf2f((u16)(wds[m] & 0xFFFFu));
            ev[2 * m + 1] = bf2f((u16)(wds[m] >> 16));
        }
    }

    float acc = 0.f;
    int cur = lutf(xi - (j0 & 31));
    const int xb = j0 & 31;
#pragma unroll
    for (int c = 0; c < 16; ++c) {
        const int bx_ = lutf(xi - (xb + c));
        if (bx_ != cur) { atomicAdd(&R[r][yj][cur], acc); acc = 0.f; cur = bx_; }
        acc += ev[c];
    }
    atomicAdd(&R[r][yj][cur], acc);

    float* rowf = &attn[((size_t)((bh << 10) + i)) << 10];
#pragma unroll
    for (int m = 0; m < 4; ++m) {
        const f32x4 o = {ev[4 * m] * inv, ev[4 * m + 1] * inv,
                         ev[4 * m + 2] * inv, ev[4 * m + 3] * inv};
        __builtin_nontemporal_store(o, (f32x4*)&rowf[j0 + 4 * m]);
    }
    __syncthreads();

    if (t < 4 * NB_) {
        const int rr = t / NB_, u = t - rr * NB_;
        const int by = u / 7, bx = u - by * 7;
        const int yi2 = (i0 + rr) >> 5;
        float s = 0.f;
#pragma unroll
        for (int yj2 = 0; yj2 < 32; ++yj2)
            if (lutf(yi2 - yj2) == by) s += R[rr][yj2][bx];
        bs[((size_t)((bh << 10) + i0 + rr)) * NB_ + u] = s * inv_s[rr];
    }
}

// ---------------------------------------------------------------------------
// K4b: pre += bs @ w_rpe_v
// ---------------------------------------------------------------------------
__global__ void irpe_addpre_k(const float* __restrict__ bs, const float* __restrict__ w_rpe_v,
                              float* __restrict__ pre) {
    __shared__ float wv[NB_ * 64];
    __shared__ float bss[16 * 52];
    const int bh = blockIdx.y, b = bh / H_, h = bh % H_;
    const int i0 = blockIdx.x * 16;
    const int t = threadIdx.x;
    for (int idx = t; idx < NB_ * 64; idx += 256) wv[idx] = w_rpe_v[idx];
    for (int idx = t; idx < 16 * NB_; idx += 256) {
        const int il = idx / NB_, u = idx - il * NB_;
        bss[il * 52 + u] = bs[((size_t)((bh << 10) + i0 + il)) * NB_ + u];
    }
    __syncthreads();
    const int il = t >> 4, d4 = (t & 15) * 4;
    f32x4 acc = {0.f, 0.f, 0.f, 0.f};
    for (int u = 0; u < NB_; ++u) {
        const float bv = bss[il * 52 + u];
        const f32x4 wvv = *(const f32x4*)&wv[u * 64 + d4];
        acc += bv * wvv;
    }
    float* p = &pre[((size_t)(b * N_ + i0 + il)) * C_ + h * HD_ + d4];
    f32x4 old = *(const f32x4*)p;
    *(f32x4*)p = old + acc;
}

// ---------------------------------------------------------------------------
// K5: projection GEMM via bf16x3 MFMA: out[m,n] = pre[m,:] . W[n,:] + b[n]
// ---------------------------------------------------------------------------
__global__ __launch_bounds__(256, 4) void irpe_proj_mfma_k(
    const float* __restrict__ A, const float* __restrict__ Bw,
    const float* __restrict__ bias, float* __restrict__ Cout) {
    __shared__ u16 Ah[4096], Al[4096], Bh[4096], Bl[4096];   // 32 KB
    const int bm = blockIdx.x * 64, bn = blockIdx.y * 64;
    const int t = threadIdx.x;
    const int w = t >> 6, lane = t & 63;
    const int ln4 = lane >> 4, lh15 = lane & 15;

    f32x4 acc[4] = {{0.f, 0.f, 0.f, 0.f}, {0.f, 0.f, 0.f, 0.f},
                    {0.f, 0.f, 0.f, 0.f}, {0.f, 0.f, 0.f, 0.f}};
    float bias_r[4];
#pragma unroll
    for (int ji = 0; ji < 4; ++ji) bias_r[ji] = bias[bn + ji * 16 + lh15];

    const int srow_ = t >> 3, sun = t & 7;
    const int ldso = srow_ * 128 + ((sun ^ (srow_ & 7)) << 4);

    for (int kt = 0; kt < C_; kt += 64) {
#pragma unroll
        for (int rep = 0; rep < 2; ++rep) {
            const int row = rep * 32 + srow_;
            const int ldo = ldso + rep * 32 * 128;
            const float* ap = &A[(size_t)(bm + row) * C_ + kt + sun * 8];
            const float* bp = &Bw[(size_t)(bn + row) * C_ + kt + sun * 8];
            const float4 a0 = *(const float4*)ap, a1 = *(const float4*)(ap + 4);
            const float4 b0 = *(const float4*)bp, b1 = *(const float4*)(bp + 4);
            const float av[8] = {a0.x, a0.y, a0.z, a0.w, a1.x, a1.y, a1.z, a1.w};
            const float bv[8] = {b0.x, b0.y, b0.z, b0.w, b1.x, b1.y, b1.z, b1.w};
            u32 ahh[4], all_[4], bhh[4], bll[4];
#pragma unroll
            for (int jj = 0; jj < 4; ++jj) {
                const u16 h0 = f2bf(av[jj * 2]), h1 = f2bf(av[jj * 2 + 1]);
                ahh[jj] = (u32)h0 | ((u32)h1 << 16);
                all_[jj] = (u32)f2bf(av[jj * 2] - bf2f(h0)) | ((u32)f2bf(av[jj * 2 + 1] - bf2f(h1)) << 16);
                const u16 g0 = f2bf(bv[jj * 2]), g1 = f2bf(bv[jj * 2 + 1]);
                bhh[jj] = (u32)g0 | ((u32)g1 << 16);
                bll[jj] = (u32)f2bf(bv[jj * 2] - bf2f(g0)) | ((u32)f2bf(bv[jj * 2 + 1] - bf2f(g1)) << 16);
            }
            *(uint4*)((char*)Ah + ldo) = make_uint4(ahh[0], ahh[1], ahh[2], ahh[3]);
            *(uint4*)((char*)Al + ldo) = make_uint4(all_[0], all_[1], all_[2], all_[3]);
            *(uint4*)((char*)Bh + ldo) = make_uint4(bhh[0], bhh[1], bhh[2], bhh[3]);
            *(uint4*)((char*)Bl + ldo) = make_uint4(bll[0], bll[1], bll[2], bll[3]);
        }
        __syncthreads();

        const int ra = w * 16 + lh15, sa = ra & 7;
        const mfrag aF0h = *(const mfrag*)((const char*)Ah + ra * 128 + ((ln4 ^ sa) << 4));
        const mfrag aF0l = *(const mfrag*)((const char*)Al + ra * 128 + ((ln4 ^ sa) << 4));
        const mfrag aF1h = *(const mfrag*)((const char*)Ah + ra * 128 + (((4 + ln4) ^ sa) << 4));
        const mfrag aF1l = *(const mfrag*)((const char*)Al + ra * 128 + (((4 + ln4) ^ sa) << 4));
#pragma unroll
        for (int ji = 0; ji < 4; ++ji) {
            const int rb = ji * 16 + lh15, sb = rb & 7;
            const mfrag bF0h = *(const mfrag*)((const char*)Bh + rb * 128 + ((ln4 ^ sb) << 4));
            const mfrag bF0l = *(const mfrag*)((const char*)Bl + rb * 128 + ((ln4 ^ sb) << 4));
            const mfrag bF1h = *(const mfrag*)((const char*)Bh + rb * 128 + (((4 + ln4) ^ sb) << 4));
            const mfrag bF1l = *(const mfrag*)((const char*)Bl + rb * 128 + (((4 + ln4) ^ sb) << 4));
            f32x4 c = acc[ji];
            c = __builtin_amdgcn_mfma_f32_16x16x32_bf16(aF0h, bF0h, c, 0, 0, 0);
            c = __builtin_amdgcn_mfma_f32_16x16x32_bf16(aF0h, bF0l, c, 0, 0, 0);
            c = __builtin_amdgcn_mfma_f32_16x16x32_bf16(aF0l, bF0h, c, 0, 0, 0);
            c = __builtin_amdgcn_mfma_f32_16x16x32_bf16(aF1h, bF1h, c, 0, 0, 0);
            c = __builtin_amdgcn_mfma_f32_16x16x32_bf16(aF1h, bF1l, c, 0, 0, 0);
            c = __builtin_amdgcn_mfma_f32_16x16x32_bf16(aF1l, bF1h, c, 0, 0, 0);
            acc[ji] = c;
        }
        __syncthreads();
    }

#pragma unroll
    for (int ji = 0; ji < 4; ++ji) {
        const int col = bn + ji * 16 + lh15;
#pragma unroll
        for (int r = 0; r < 4; ++r) {
            const int row = bm + w * 16 + ln4 * 4 + r;
            Cout[(size_t)row * C_ + col] = acc[ji][r] + bias_r[ji];
        }
    }
}

// ---------------------------------------------------------------------------
extern "C" void kernel_launch(void* const* d_in, const int* in_sizes, int n_in,
                              void* d_out, int out_size, void* d_ws, size_t ws_size,
                              hipStream_t stream) {
    const float* q       = (const float*)d_in[0];
    const float* k       = (const float*)d_in[1];
    const float* v       = (const float*)d_in[2];
    const float* w_rpe_q = (const float*)d_in[3];
    const float* w_rpe_k = (const float*)d_in[4];
    const float* w_rpe_v = (const float*)d_in[5];
    const float* proj_w  = (const float*)d_in[6];
    const float* proj_b  = (const float*)d_in[7];

    float* out  = (float*)d_out;               // [B,N,C]
    float* attn = out + (size_t)B_ * N_ * C_;  // [B,H,N,N]

    char* ws = (char*)d_ws;
    float* tk    = (float*)ws; ws += (size_t)BH_ * N_ * NB_ * 4;
    u16*   tqT   = (u16*)ws;   ws += (size_t)BH_ * NB_ * N_ * 2;
    float* pre   = (float*)ws; ws += (size_t)B_ * N_ * C_ * 4;
    float* s_arr = (float*)ws; ws += (size_t)BH_ * N_ * 4;
    float* bs    = (float*)ws; ws += (size_t)BH_ * N_ * NB_ * 4;
    u16* qh  = (u16*)ws; ws += (size_t)BH_ * N_ * 64 * 2;
    u16* ql  = (u16*)ws; ws += (size_t)BH_ * N_ * 64 * 2;
    u16* kh  = (u16*)ws; ws += (size_t)BH_ * N_ * 64 * 2;
    u16* kl  = (u16*)ws; ws += (size_t)BH_ * N_ * 64 * 2;
    u16* vth = (u16*)ws; ws += (size_t)BH_ * 64 * N_ * 2;

    irpe_prep_k<<<dim3(N_ / 4, BH_), 256, 0, stream>>>(q, k, w_rpe_q, w_rpe_k,
                                                       qh, ql, kh, kl, tk, tqT);
    irpe_vt_k<<<dim3(16, BH_), 256, 0, stream>>>(v, vth);

    irpe_attn_mfma_k<<<BH_ * (N_ / 64), 256, 0, stream>>>(
        qh, ql, kh, kl, vth, tk, tqT, (u16*)attn, s_arr, pre);

    irpe_rescale_bucket_k<<<dim3(N_ / 4, BH_), 256, 0, stream>>>(attn, s_arr, bs);
    irpe_addpre_k<<<dim3(N_ / 16, BH_), 256, 0, stream>>>(bs, w_rpe_v, pre);
    irpe_proj_mfma_k<<<dim3((B_ * N_) / 64, C_ / 64), 256, 0, stream>>>(pre, proj_w, proj_b, out);
}

// Round 11
// 565.427 us; speedup vs baseline: 1.3643x; 1.3630x over previous
//
#include <hip/hip_runtime.h>

#define B_ 8
#define N_ 1024
#define C_ 768
#define H_ 12
#define HD_ 64
#define NB_ 49
#define BH_ 96
#define SCALE_ 0.125f

typedef unsigned int u32;
typedef unsigned short u16;
typedef __attribute__((ext_vector_type(8))) short mfrag;   // 8 bf16 (4 VGPRs)
typedef __attribute__((ext_vector_type(4))) float f32x4;
typedef __attribute__((ext_vector_type(4))) u32 u32x4;

__device__ __forceinline__ u16 f2bf(float x) {             // f32 -> bf16 (RNE)
    u32 u = __float_as_uint(x);
    u32 r = u + 0x7FFFu + ((u >> 16) & 1u);
    return (u16)(r >> 16);
}
__device__ __forceinline__ float bf2f(u16 h) { return __uint_as_float(((u32)h) << 16); }

// iRPE piecewise bucket (closed form for ALPHA=1.9, BETA=3.8, GAMMA=15.2):
// |d|: 0->0, 1->1, 2,3->2, >=4->3 ; bucket = 3 + sign(d)*g  (in [0,6])
__device__ __forceinline__ int lutf(int d) {
    int a = d < 0 ? -d : d;
    int gg = (a < 2 ? a : 2) + (a >= 4 ? 1 : 0);
    return d < 0 ? 3 - gg : 3 + gg;
}

// ---------------------------------------------------------------------------
// K1 (fused prep): q,k bf16 hi/lo buffers; tk f32 [bh][i][49];
// tqT bf16 [bh][49][1024] (pre-scaled).
// ---------------------------------------------------------------------------
__global__ void irpe_prep_k(const float* __restrict__ q, const float* __restrict__ k,
                            const float* __restrict__ w_rpe_q, const float* __restrict__ w_rpe_k,
                            u16* __restrict__ qh, u16* __restrict__ ql,
                            u16* __restrict__ kh, u16* __restrict__ kl,
                            float* __restrict__ tk, u16* __restrict__ tqT) {
    const int bh = blockIdx.y, b = bh / H_, h = bh % H_;
    const int row0 = blockIdx.x * 4;
    __shared__ float qs[4][HD_], ks[4][HD_];
    const int t = threadIdx.x;
    {
        const int r = t >> 6, d = t & 63;
        const size_t gi = ((size_t)(b * N_ + row0 + r)) * C_ + h * HD_ + d;
        const float vq = q[gi], vk = k[gi];
        qs[r][d] = vq;
        ks[r][d] = vk;
        const size_t so = (((size_t)(bh << 10)) + row0 + r) * 64 + d;
        const u16 qhi = f2bf(vq), khi = f2bf(vk);
        qh[so] = qhi; ql[so] = f2bf(vq - bf2f(qhi));
        kh[so] = khi; kl[so] = f2bf(vk - bf2f(khi));
    }
    __syncthreads();
    if (t < 4 * NB_) {
        const int r = t / NB_, u = t - r * NB_;
        float dk = 0.f, dq = 0.f;
#pragma unroll
        for (int d = 0; d < HD_; ++d) {
            dk = fmaf(qs[r][d], w_rpe_k[d * NB_ + u], dk);
            dq = fmaf(ks[r][d], w_rpe_q[d * NB_ + u], dq);
        }
        tk[((size_t)bh * N_ + row0 + r) * NB_ + u] = dk;
        tqT[(((size_t)bh * NB_ + u) << 10) + row0 + r] = f2bf(dq * SCALE_);
    }
}

// ---------------------------------------------------------------------------
// K0b: v -> transposed bf16 (hi only) [bh][64(d)][1024(j)]
// ---------------------------------------------------------------------------
__global__ void irpe_vt_k(const float* __restrict__ v, u16* __restrict__ vth) {
    __shared__ float tile[64][65];
    const int bh = blockIdx.y, jc0 = blockIdx.x * 64;
    const int b = bh / H_, h = bh % H_;
    const int t = threadIdx.x;
#pragma unroll
    for (int rep = 0; rep < 4; ++rep) {
        const int fl = rep * 256 + t;
        const int jr = fl >> 4, c4 = (fl & 15) * 4;
        const float4 x = *(const float4*)&v[((size_t)(b * N_ + jc0 + jr)) * C_ + h * HD_ + c4];
        tile[jr][c4] = x.x; tile[jr][c4 + 1] = x.y; tile[jr][c4 + 2] = x.z; tile[jr][c4 + 3] = x.w;
    }
    __syncthreads();
    const int d = t >> 2, jq = (t & 3) * 16;
    u32 ph[8];
#pragma unroll
    for (int jj = 0; jj < 8; ++jj) {
        const u16 h0 = f2bf(tile[jq + jj * 2][d]);
        const u16 h1 = f2bf(tile[jq + jj * 2 + 1][d]);
        ph[jj] = (u32)h0 | ((u32)h1 << 16);
    }
    const size_t dst = (((size_t)bh * 64 + d) << 10) + jc0 + jq;
    *(uint4*)&vth[dst] = make_uint4(ph[0], ph[1], ph[2], ph[3]);
    *(uint4*)&vth[dst + 8] = make_uint4(ph[4], ph[5], ph[6], ph[7]);
}

// ---------------------------------------------------------------------------
// K_main: single-sweep fused attention, bf16x3 QK / bf16 PV, wave-local P.
// (unchanged from R10 — passed, ~240 us)
// ---------------------------------------------------------------------------
__global__ __launch_bounds__(256, 3) void irpe_attn_mfma_k(
    const u16* __restrict__ qh_g, const u16* __restrict__ ql_g,
    const u16* __restrict__ kh_g, const u16* __restrict__ kl_g,
    const u16* __restrict__ vth_g,
    const float* __restrict__ tk, const u16* __restrict__ tqT,
    u16* __restrict__ e_g, float* __restrict__ s_arr, float* __restrict__ pre) {
    __shared__ u16 kAh[4096], kAl[4096];     // K  [64 j][64 d] swizzled  16 KB
    __shared__ u16 vAh[4096];                // vT [64 d][64 j] swizzled   8 KB
    __shared__ u16 awh[4096];                // P  [64 i][64 j] swizzled   8 KB
    __shared__ u16 tq_su[NB_ * 72];          // [49][72] bf16             6.9 KB
    __shared__ u16 tks_s[64 * 50];           // [64][50] bf16            6.25 KB

    const int gid = blockIdx.x;
    const int xcd = gid & 7, L = gid >> 3;
    const int bh = xcd * 12 + (L >> 4);      // 12 bh per XCD, itile-inner
    const int itile = L & 15;
    const int b = bh / H_, h = bh % H_;
    const int i0 = itile * 64;
    const int t = threadIdx.x;
    const int w = t >> 6, lane = t & 63;
    const int ln4 = lane >> 4, lh15 = lane & 15;
    const int yi = itile * 2 + (w >> 1);     // wave-uniform grid-y of its rows
    const size_t tqbase = (size_t)bh * NB_ * 1024;
    const int arow0 = (bh << 10) + i0;

    // ---- persistent Q fragments ----
    mfrag qAh[2], qAl[2];
#pragma unroll
    for (int ks = 0; ks < 2; ++ks) {
        const size_t qa = (((size_t)(bh << 10) + i0 + w * 16 + lh15) << 6) + (ln4 << 3) + (ks << 5);
        qAh[ks] = *(const mfrag*)&qh_g[qa];
        qAl[ks] = *(const mfrag*)&ql_g[qa];
    }

    // ---- chunk-invariant bucket-x ----
    int bxp[2][4];
#pragma unroll
    for (int jh = 0; jh < 2; ++jh)
#pragma unroll
        for (int r = 0; r < 4; ++r) {
            const int xi = (w & 1) * 16 + ln4 * 4 + r;
            bxp[jh][r] = lutf(xi - (jh * 16 + lh15));
        }

    // ---- prefetch regs for chunk 0 ----
    mfrag kstg[4], vstg[2];
#pragma unroll
    for (int rep = 0; rep < 2; ++rep) {
        const int unit = rep * 256 + t;
        const int row = unit >> 3, un = unit & 7;
        const size_t ka = (((size_t)(bh << 10) + row) << 6) + un * 8;
        kstg[rep * 2] = *(const mfrag*)&kh_g[ka];
        kstg[rep * 2 + 1] = *(const mfrag*)&kl_g[ka];
        vstg[rep] = *(const mfrag*)&vth_g[(((size_t)(bh * 64) + row) << 10) + un * 8];
    }
    u32x4 tqpre[2];
    {
        const int u0 = t >> 3, c0 = t & 7;
        tqpre[0] = *(const u32x4*)&tqT[tqbase + ((size_t)u0 << 10) + c0 * 8];
        if (t < 136) {
            const int u1 = (256 + t) >> 3, c1 = t & 7;
            tqpre[1] = *(const u32x4*)&tqT[tqbase + ((size_t)u1 << 10) + c1 * 8];
        }
    }

    // ---- tks -> LDS bf16 (once) ----
    {
        const size_t tkb = ((size_t)(bh << 10) + i0) * NB_;
        for (int idx = t; idx < 64 * NB_; idx += 256) {
            const int row = idx / NB_, u = idx - row * NB_;
            tks_s[row * 50 + u] = f2bf(tk[tkb + idx]);
        }
    }

    f32x4 apv[4] = {{0.f, 0.f, 0.f, 0.f}, {0.f, 0.f, 0.f, 0.f},
                    {0.f, 0.f, 0.f, 0.f}, {0.f, 0.f, 0.f, 0.f}};
    float srow[4] = {0.f, 0.f, 0.f, 0.f};

#pragma unroll 1
    for (int ch = 0; ch < 16; ++ch) {
        const int jc0 = ch << 6;

        // ---- stage K/V/tq from regs -> LDS ----
#pragma unroll
        for (int rep = 0; rep < 2; ++rep) {
            const int unit = rep * 256 + t;
            const int row = unit >> 3, un = unit & 7;
            const int ldso = row * 128 + ((un ^ (row & 7)) << 4);
            *(mfrag*)((char*)kAh + ldso) = kstg[rep * 2];
            *(mfrag*)((char*)kAl + ldso) = kstg[rep * 2 + 1];
            *(mfrag*)((char*)vAh + ldso) = vstg[rep];
        }
        {
            const int u0 = t >> 3, c0 = t & 7;
            *(u32x4*)((char*)tq_su + u0 * 144 + c0 * 16) = tqpre[0];
            if (t < 136) {
                const int u1 = (256 + t) >> 3;
                *(u32x4*)((char*)tq_su + u1 * 144 + (t & 7) * 16) = tqpre[1];
            }
        }
        __syncthreads();   // B1: stage visible (loads issued a chunk ago)

        // ---- QK (bf16x3) ----
        f32x4 aq[4];
        __builtin_amdgcn_s_setprio(1);
#pragma unroll
        for (int ji = 0; ji < 4; ++ji) {
            const int rb = ji * 16 + lh15, swb = rb & 7;
            const mfrag bh0 = *(const mfrag*)((const char*)kAh + rb * 128 + ((ln4 ^ swb) << 4));
            const mfrag bl0 = *(const mfrag*)((const char*)kAl + rb * 128 + ((ln4 ^ swb) << 4));
            const mfrag bh1 = *(const mfrag*)((const char*)kAh + rb * 128 + (((4 + ln4) ^ swb) << 4));
            const mfrag bl1 = *(const mfrag*)((const char*)kAl + rb * 128 + (((4 + ln4) ^ swb) << 4));
            f32x4 c = {0.f, 0.f, 0.f, 0.f};
            c = __builtin_amdgcn_mfma_f32_16x16x32_bf16(qAh[0], bh0, c, 0, 0, 0);
            c = __builtin_amdgcn_mfma_f32_16x16x32_bf16(qAh[0], bl0, c, 0, 0, 0);
            c = __builtin_amdgcn_mfma_f32_16x16x32_bf16(qAl[0], bh0, c, 0, 0, 0);
            c = __builtin_amdgcn_mfma_f32_16x16x32_bf16(qAh[1], bh1, c, 0, 0, 0);
            c = __builtin_amdgcn_mfma_f32_16x16x32_bf16(qAh[1], bl1, c, 0, 0, 0);
            c = __builtin_amdgcn_mfma_f32_16x16x32_bf16(qAl[1], bh1, c, 0, 0, 0);
            aq[ji] = c;
        }
        __builtin_amdgcn_s_setprio(0);

        // ---- issue prefetch for ch+1 ----
        if (ch < 15) {
            const int jc1 = jc0 + 64;
#pragma unroll
            for (int rep = 0; rep < 2; ++rep) {
                const int unit = rep * 256 + t;
                const int row = unit >> 3, un = unit & 7;
                const size_t ka = (((size_t)(bh << 10) + jc1 + row) << 6) + un * 8;
                kstg[rep * 2] = *(const mfrag*)&kh_g[ka];
                kstg[rep * 2 + 1] = *(const mfrag*)&kl_g[ka];
                vstg[rep] = *(const mfrag*)&vth_g[(((size_t)(bh * 64) + row) << 10) + jc1 + un * 8];
            }
            const int u0 = t >> 3, c0 = t & 7;
            tqpre[0] = *(const u32x4*)&tqT[tqbase + ((size_t)u0 << 10) + jc1 + c0 * 8];
            if (t < 136) {
                const int u1 = (256 + t) >> 3;
                tqpre[1] = *(const u32x4*)&tqT[tqbase + ((size_t)u1 << 10) + jc1 + (t & 7) * 8];
            }
        }

        // ---- bias + exp -> awh (wave-local; no global store here) ----
#pragma unroll
        for (int ji = 0; ji < 4; ++ji) {
            const int yj = (ch << 1) + (ji >> 1);
            const int by7 = 7 * lutf(yi - yj);
            const int jl = ji * 16 + lh15;
#pragma unroll
            for (int r = 0; r < 4; ++r) {
                const int il = w * 16 + ln4 * 4 + r;
                const int bij = by7 + bxp[ji & 1][r];
                const float e = __expf(fmaf(aq[ji][r], SCALE_,
                                            bf2f(tks_s[il * 50 + bij]) + bf2f(tq_su[(48 - bij) * 72 + jl])));
                srow[r] += e;
                const int off = il * 128 + ((jl << 1) ^ ((il & 7) << 4));
                *(u16*)((char*)awh + off) = f2bf(e);
            }
        }
        // wave-local aw: compiler inserts lgkmcnt wait before PV reads

        // ---- PV (bf16) ----
        {
            const int rowA = w * 16 + lh15, sa = (rowA & 7) << 4;
            mfrag pah[2];
#pragma unroll
            for (int ks = 0; ks < 2; ++ks)
                pah[ks] = *(const mfrag*)((const char*)awh + rowA * 128 + ((((ln4 << 4) + (ks << 6))) ^ sa));
            __builtin_amdgcn_s_setprio(1);
#pragma unroll
            for (int di = 0; di < 4; ++di) {
                const int rv = di * 16 + lh15, swv = rv & 7;
                const mfrag vh0 = *(const mfrag*)((const char*)vAh + rv * 128 + ((ln4 ^ swv) << 4));
                const mfrag vh1 = *(const mfrag*)((const char*)vAh + rv * 128 + (((4 + ln4) ^ swv) << 4));
                f32x4 c = apv[di];
                c = __builtin_amdgcn_mfma_f32_16x16x32_bf16(pah[0], vh0, c, 0, 0, 0);
                c = __builtin_amdgcn_mfma_f32_16x16x32_bf16(pah[1], vh1, c, 0, 0, 0);
                apv[di] = c;
            }
            __builtin_amdgcn_s_setprio(0);
        }

        // ---- batched e store: own-wave awh rows -> e_g (bf16, nt) ----
#pragma unroll
        for (int rep = 0; rep < 2; ++rep) {
            const int unit = rep * 64 + lane;          // 128 units x 16B = own 2KB
            const int rowl = unit >> 3, un = unit & 7;
            const int row = w * 16 + rowl;
            const u32x4 val = *(const u32x4*)((const char*)awh + row * 128 + ((un << 4) ^ ((row & 7) << 4)));
            __builtin_nontemporal_store(val,
                (u32x4*)&e_g[((size_t)(arow0 + row) << 11) + jc0 + un * 8]);
        }
        __syncthreads();   // B2: LDS reads done; prefetch/stores drained
    }

    // ---- epilogue: row sums ----
    float inv[4];
#pragma unroll
    for (int r = 0; r < 4; ++r) {
        float s = srow[r];
        s += __shfl_xor(s, 1); s += __shfl_xor(s, 2);
        s += __shfl_xor(s, 4); s += __shfl_xor(s, 8);
        inv[r] = 1.0f / s;
        if (lh15 == 0) s_arr[((size_t)bh << 10) + i0 + w * 16 + ln4 * 4 + r] = s;
    }

    // ---- normalize + write pre (rpe_v added later from bs) ----
#pragma unroll
    for (int di = 0; di < 4; ++di) {
        const int d = di * 16 + lh15;
#pragma unroll
        for (int r = 0; r < 4; ++r) {
            const int i = i0 + w * 16 + ln4 * 4 + r;
            pre[((size_t)(b * N_ + i)) * C_ + h * HD_ + d] = apv[di][r] * inv[r];
        }
    }
}

// ---------------------------------------------------------------------------
// K4 v2: expand bf16 e (in-place in attn buffer) -> normalized f32 attn,
// AND compute bucket sums bs[bh][i][49].
// 8 rows/block (wave w does rows w and w+4), XCD-pinned 1D grid matching the
// main kernel's bh->XCD map. Cached (non-nt) stores so L2 merges the strided
// 16B pieces. bs tail uses a shared lutyj[32] table (block-uniform yi2).
// In-place safety: each wave loads its row's full e before storing any of it.
// ---------------------------------------------------------------------------
__global__ __launch_bounds__(256) void irpe_rescale_bucket_k(
    float* __restrict__ attn, const float* __restrict__ s_arr, float* __restrict__ bs) {
    __shared__ float R[8][32][8];    // 8 KB
    __shared__ float inv_s[8];
    __shared__ int lutyj[32];

    const int gid = blockIdx.x;                 // 12288 blocks
    const int xcd = gid & 7, loc = gid >> 3;    // loc in [0,1536)
    const int bh = xcd * 12 + (loc >> 7);       // 128 blocks per bh
    const int i0 = (loc & 127) * 8;
    const int t = threadIdx.x;
    const int w = t >> 6, lane = t & 63;
    const int yi2 = i0 >> 5;                    // uniform for all 8 rows

    for (int idx = t; idx < 8 * 32 * 8; idx += 256) ((float*)R)[idx] = 0.f;
    if (t < 8) inv_s[t] = 1.0f / s_arr[((size_t)bh << 10) + i0 + t];
    if (t < 32) lutyj[t] = lutf(yi2 - t);
    __syncthreads();

    const int j0 = lane * 16;
    const int yj = j0 >> 5;
    const int xb = j0 & 31;

#pragma unroll
    for (int rp = 0; rp < 2; ++rp) {
        const int rr = rp * 4 + w;
        const int i = i0 + rr;
        const int xi = i & 31;
        const float inv = inv_s[rr];
        const u16* erow = (const u16*)attn + (((size_t)((bh << 10) + i)) << 11);
        const u32x4 ea = *(const u32x4*)&erow[j0];
        const u32x4 eb = *(const u32x4*)&erow[j0 + 8];
        float ev[16];
        {
            const u32 wds[8] = {ea.x, ea.y, ea.z, ea.w, eb.x, eb.y, eb.z, eb.w};
#pragma unroll
            for (int m = 0; m < 8; ++m) {
                ev[2 * m] = bf2f((u16)(wds[m] & 0xFFFFu));
                ev[2 * m + 1] = bf2f((u16)(wds[m] >> 16));
            }
        }

        // bucket segment sums (run-combined, <=2-way LDS atomic conflicts)
        float acc = 0.f;
        int cur = lutf(xi - xb);
#pragma unroll
        for (int c = 0; c < 16; ++c) {
            const int bx_ = lutf(xi - (xb + c));
            if (bx_ != cur) { atomicAdd(&R[rr][yj][cur], acc); acc = 0.f; cur = bx_; }
            acc += ev[c];
        }
        atomicAdd(&R[rr][yj][cur], acc);

        // normalized f32 write (cached: L2 merges the strided 16B pieces)
        float* rowf = &attn[((size_t)((bh << 10) + i)) << 10];
#pragma unroll
        for (int m = 0; m < 4; ++m) {
            const f32x4 o = {ev[4 * m] * inv, ev[4 * m + 1] * inv,
                             ev[4 * m + 2] * inv, ev[4 * m + 3] * inv};
            *(f32x4*)&rowf[j0 + 4 * m] = o;
        }
    }
    __syncthreads();

    for (int idx = t; idx < 8 * NB_; idx += 256) {
        const int rr = idx / NB_, u = idx - rr * NB_;
        const int by = u / 7, bx = u - by * 7;
        float s = 0.f;
#pragma unroll
        for (int yj2 = 0; yj2 < 32; ++yj2)
            if (lutyj[yj2] == by) s += R[rr][yj2][bx];
        bs[((size_t)((bh << 10) + i0 + rr)) * NB_ + u] = s * inv_s[rr];
    }
}

// ---------------------------------------------------------------------------
// K4b: pre += bs @ w_rpe_v
// ---------------------------------------------------------------------------
__global__ void irpe_addpre_k(const float* __restrict__ bs, const float* __restrict__ w_rpe_v,
                              float* __restrict__ pre) {
    __shared__ float wv[NB_ * 64];
    __shared__ float bss[16 * 52];
    const int bh = blockIdx.y, b = bh / H_, h = bh % H_;
    const int i0 = blockIdx.x * 16;
    const int t = threadIdx.x;
    for (int idx = t; idx < NB_ * 64; idx += 256) wv[idx] = w_rpe_v[idx];
    for (int idx = t; idx < 16 * NB_; idx += 256) {
        const int il = idx / NB_, u = idx - il * NB_;
        bss[il * 52 + u] = bs[((size_t)((bh << 10) + i0 + il)) * NB_ + u];
    }
    __syncthreads();
    const int il = t >> 4, d4 = (t & 15) * 4;
    f32x4 acc = {0.f, 0.f, 0.f, 0.f};
    for (int u = 0; u < NB_; ++u) {
        const float bv = bss[il * 52 + u];
        const f32x4 wvv = *(const f32x4*)&wv[u * 64 + d4];
        acc += bv * wvv;
    }
    float* p = &pre[((size_t)(b * N_ + i0 + il)) * C_ + h * HD_ + d4];
    f32x4 old = *(const f32x4*)p;
    *(f32x4*)p = old + acc;
}

// ---------------------------------------------------------------------------
// K5: projection GEMM via bf16x3 MFMA: out[m,n] = pre[m,:] . W[n,:] + b[n]
// ---------------------------------------------------------------------------
__global__ __launch_bounds__(256, 4) void irpe_proj_mfma_k(
    const float* __restrict__ A, const float* __restrict__ Bw,
    const float* __restrict__ bias, float* __restrict__ Cout) {
    __shared__ u16 Ah[4096], Al[4096], Bh[4096], Bl[4096];   // 32 KB
    const int bm = blockIdx.x * 64, bn = blockIdx.y * 64;
    const int t = threadIdx.x;
    const int w = t >> 6, lane = t & 63;
    const int ln4 = lane >> 4, lh15 = lane & 15;

    f32x4 acc[4] = {{0.f, 0.f, 0.f, 0.f}, {0.f, 0.f, 0.f, 0.f},
                    {0.f, 0.f, 0.f, 0.f}, {0.f, 0.f, 0.f, 0.f}};
    float bias_r[4];
#pragma unroll
    for (int ji = 0; ji < 4; ++ji) bias_r[ji] = bias[bn + ji * 16 + lh15];

    const int srow_ = t >> 3, sun = t & 7;
    const int ldso = srow_ * 128 + ((sun ^ (srow_ & 7)) << 4);

    for (int kt = 0; kt < C_; kt += 64) {
#pragma unroll
        for (int rep = 0; rep < 2; ++rep) {
            const int row = rep * 32 + srow_;
            const int ldo = ldso + rep * 32 * 128;
            const float* ap = &A[(size_t)(bm + row) * C_ + kt + sun * 8];
            const float* bp = &Bw[(size_t)(bn + row) * C_ + kt + sun * 8];
            const float4 a0 = *(const float4*)ap, a1 = *(const float4*)(ap + 4);
            const float4 b0 = *(const float4*)bp, b1 = *(const float4*)(bp + 4);
            const float av[8] = {a0.x, a0.y, a0.z, a0.w, a1.x, a1.y, a1.z, a1.w};
            const float bv[8] = {b0.x, b0.y, b0.z, b0.w, b1.x, b1.y, b1.z, b1.w};
            u32 ahh[4], all_[4], bhh[4], bll[4];
#pragma unroll
            for (int jj = 0; jj < 4; ++jj) {
                const u16 h0 = f2bf(av[jj * 2]), h1 = f2bf(av[jj * 2 + 1]);
                ahh[jj] = (u32)h0 | ((u32)h1 << 16);
                all_[jj] = (u32)f2bf(av[jj * 2] - bf2f(h0)) | ((u32)f2bf(av[jj * 2 + 1] - bf2f(h1)) << 16);
                const u16 g0 = f2bf(bv[jj * 2]), g1 = f2bf(bv[jj * 2 + 1]);
                bhh[jj] = (u32)g0 | ((u32)g1 << 16);
                bll[jj] = (u32)f2bf(bv[jj * 2] - bf2f(g0)) | ((u32)f2bf(bv[jj * 2 + 1] - bf2f(g1)) << 16);
            }
            *(uint4*)((char*)Ah + ldo) = make_uint4(ahh[0], ahh[1], ahh[2], ahh[3]);
            *(uint4*)((char*)Al + ldo) = make_uint4(all_[0], all_[1], all_[2], all_[3]);
            *(uint4*)((char*)Bh + ldo) = make_uint4(bhh[0], bhh[1], bhh[2], bhh[3]);
            *(uint4*)((char*)Bl + ldo) = make_uint4(bll[0], bll[1], bll[2], bll[3]);
        }
        __syncthreads();

        const int ra = w * 16 + lh15, sa = ra & 7;
        const mfrag aF0h = *(const mfrag*)((const char*)Ah + ra * 128 + ((ln4 ^ sa) << 4));
        const mfrag aF0l = *(const mfrag*)((const char*)Al + ra * 128 + ((ln4 ^ sa) << 4));
        const mfrag aF1h = *(const mfrag*)((const char*)Ah + ra * 128 + (((4 + ln4) ^ sa) << 4));
        const mfrag aF1l = *(const mfrag*)((const char*)Al + ra * 128 + (((4 + ln4) ^ sa) << 4));
#pragma unroll
        for (int ji = 0; ji < 4; ++ji) {
            const int rb = ji * 16 + lh15, sb = rb & 7;
            const mfrag bF0h = *(const mfrag*)((const char*)Bh + rb * 128 + ((ln4 ^ sb) << 4));
            const mfrag bF0l = *(const mfrag*)((const char*)Bl + rb * 128 + ((ln4 ^ sb) << 4));
            const mfrag bF1h = *(const mfrag*)((const char*)Bh + rb * 128 + (((4 + ln4) ^ sb) << 4));
            const mfrag bF1l = *(const mfrag*)((const char*)Bl + rb * 128 + (((4 + ln4) ^ sb) << 4));
            f32x4 c = acc[ji];
            c = __builtin_amdgcn_mfma_f32_16x16x32_bf16(aF0h, bF0h, c, 0, 0, 0);
            c = __builtin_amdgcn_mfma_f32_16x16x32_bf16(aF0h, bF0l, c, 0, 0, 0);
            c = __builtin_amdgcn_mfma_f32_16x16x32_bf16(aF0l, bF0h, c, 0, 0, 0);
            c = __builtin_amdgcn_mfma_f32_16x16x32_bf16(aF1h, bF1h, c, 0, 0, 0);
            c = __builtin_amdgcn_mfma_f32_16x16x32_bf16(aF1h, bF1l, c, 0, 0, 0);
            c = __builtin_amdgcn_mfma_f32_16x16x32_bf16(aF1l, bF1h, c, 0, 0, 0);
            acc[ji] = c;
        }
        __syncthreads();
    }

#pragma unroll
    for (int ji = 0; ji < 4; ++ji) {
        const int col = bn + ji * 16 + lh15;
#pragma unroll
        for (int r = 0; r < 4; ++r) {
            const int row = bm + w * 16 + ln4 * 4 + r;
            Cout[(size_t)row * C_ + col] = acc[ji][r] + bias_r[ji];
        }
    }
}

// ---------------------------------------------------------------------------
extern "C" void kernel_launch(void* const* d_in, const int* in_sizes, int n_in,
                              void* d_out, int out_size, void* d_ws, size_t ws_size,
                              hipStream_t stream) {
    const float* q       = (const float*)d_in[0];
    const float* k       = (const float*)d_in[1];
    const float* v       = (const float*)d_in[2];
    const float* w_rpe_q = (const float*)d_in[3];
    const float* w_rpe_k = (const float*)d_in[4];
    const float* w_rpe_v = (const float*)d_in[5];
    const float* proj_w  = (const float*)d_in[6];
    const float* proj_b  = (const float*)d_in[7];

    float* out  = (float*)d_out;               // [B,N,C]
    float* attn = out + (size_t)B_ * N_ * C_;  // [B,H,N,N]

    char* ws = (char*)d_ws;
    float* tk    = (float*)ws; ws += (size_t)BH_ * N_ * NB_ * 4;
    u16*   tqT   = (u16*)ws;   ws += (size_t)BH_ * NB_ * N_ * 2;
    float* pre   = (float*)ws; ws += (size_t)B_ * N_ * C_ * 4;
    float* s_arr = (float*)ws; ws += (size_t)BH_ * N_ * 4;
    float* bs    = (float*)ws; ws += (size_t)BH_ * N_ * NB_ * 4;
    u16* qh  = (u16*)ws; ws += (size_t)BH_ * N_ * 64 * 2;
    u16* ql  = (u16*)ws; ws += (size_t)BH_ * N_ * 64 * 2;
    u16* kh  = (u16*)ws; ws += (size_t)BH_ * N_ * 64 * 2;
    u16* kl  = (u16*)ws; ws += (size_t)BH_ * N_ * 64 * 2;
    u16* vth = (u16*)ws; ws += (size_t)BH_ * 64 * N_ * 2;

    irpe_prep_k<<<dim3(N_ / 4, BH_), 256, 0, stream>>>(q, k, w_rpe_q, w_rpe_k,
                                                       qh, ql, kh, kl, tk, tqT);
    irpe_vt_k<<<dim3(16, BH_), 256, 0, stream>>>(v, vth);

    irpe_attn_mfma_k<<<BH_ * (N_ / 64), 256, 0, stream>>>(
        qh, ql, kh, kl, vth, tk, tqT, (u16*)attn, s_arr, pre);

    irpe_rescale_bucket_k<<<BH_ * (N_ / 8), 256, 0, stream>>>(attn, s_arr, bs);
    irpe_addpre_k<<<dim3(N_ / 16, BH_), 256, 0, stream>>>(bs, w_rpe_v, pre);
    irpe_proj_mfma_k<<<dim3((B_ * N_) / 64, C_ / 64), 256, 0, stream>>>(pre, proj_w, proj_b, out);
}